// Round 11
// baseline (186.403 us; speedup 1.0000x reference)
//
#include <hip/hip_runtime.h>

#define NSEG   4096
#define GRID_B 256
#define BLK_B  1024
#define COPYU  (2 * NSEG)           // u64 per copy: A (4x16b Q10) | C (Q20|cnt)
#define PADU   (NSEG + 2)
#define LAMBDA1 0.8f
#define LAMBDA2 0.2f
#define FIXA   1024.0f              // Q10 for s1 fields
#define INVA   (1.0 / 1024.0)
#define FIXC   1048576.0f           // Q20 for S2
#define INVC   (1.0 / 1048576.0)

// r10 post-mortem: 3->2 atomics/px moved dur_us by -0.8us (167.4->166.6):
// main_r9 ~= main_r10 ~= ~50us. The per-atomic-op model (calibrated r6->r9,
// 202us -> <56us) STOPS predicting here -> unknown ~50us wall. This round:
// ablation probe (4th kernel, discarded output) = identical loop with atomics
// replaced by asm keep-alives. dur_r11 - dur_r10 = atomic-free floor F.
//   F ~ 45-55: streaming loop is the wall -> attack load pipeline next.
//   F ~ 15-25: atomics still ~25-35us -> global-atomic / split-hist next.

__launch_bounds__(BLK_B, 1)
__global__ void mrf_main(const float* __restrict__ logits,
                         const int* __restrict__ sp,
                         long long npix,
                         unsigned long long* __restrict__ copies,
                         unsigned long long* __restrict__ Rc,
                         unsigned* __restrict__ Rs1,
                         float* __restrict__ Epart,
                         int direct)
{
    __shared__ alignas(16) unsigned long long hist[2 * PADU];
    __shared__ float wred[BLK_B / 64];

    for (int i = threadIdx.x; i < 2 * PADU; i += BLK_B) hist[i] = 0ull;
    __syncthreads();

    float ent = 0.f;

    auto proc = [&](float x0, float x1, float x2, float x3, float x4, int seg) {
        float m  = fmaxf(fmaxf(x0, x1), fmaxf(fmaxf(x2, x3), x4));
        float d0 = x0 - m, d1 = x1 - m, d2 = x2 - m, d3 = x3 - m, d4 = x4 - m;
        float t0 = __expf(d0), t1 = __expf(d1), t2 = __expf(d2),
              t3 = __expf(d3), t4 = __expf(d4);
        float S = ((t0 + t1) + (t2 + t3)) + t4;
        float r = __builtin_amdgcn_rcpf(S);
        float p0 = t0 * r, p1 = t1 * r, p2 = t2 * r, p3 = t3 * r, p4 = t4 * r;
        ent += __logf(S) - r * (t0 * d0 + t1 * d1 + t2 * d2 + t3 * d3 + t4 * d4);
        float s2 = ((p0 * p0 + p1 * p1) + (p2 * p2 + p3 * p3)) + p4 * p4;
        unsigned long long q0 = (unsigned)(p0 * FIXA + 0.5f);
        unsigned long long q1 = (unsigned)(p1 * FIXA + 0.5f);
        unsigned long long q2 = (unsigned)(p2 * FIXA + 0.5f);
        unsigned long long q3 = (unsigned)(p3 * FIXA + 0.5f);
        unsigned long long qs = (unsigned)(s2 * FIXC + 0.5f);
        atomicAdd(&hist[seg], q0 | (q1 << 16) | (q2 << 32) | (q3 << 48));
        atomicAdd(&hist[PADU + seg], 0x100000000ull | qs);   // cnt in hi word
    };

    long long tid    = (long long)blockIdx.x * BLK_B + threadIdx.x;
    long long stride = (long long)gridDim.x * BLK_B;
    long long npair  = npix >> 1;

    float4 a, b, c; int2 ss;
    long long pp = tid;
    if (pp < npair) {
        const float4* base = (const float4*)(logits + pp * 12);
        a = base[0]; b = base[1]; c = base[2];
        ss = *(const int2*)(sp + pp * 2);
    }
    while (pp < npair) {
        long long nx = pp + stride;
        float4 na, nb, nc2; int2 nss;
        if (nx < npair) {
            const float4* base = (const float4*)(logits + nx * 12);
            na = base[0]; nb = base[1]; nc2 = base[2];
            nss = *(const int2*)(sp + nx * 2);
        }
        proc(a.x, a.y, a.z, a.w, b.x, ss.x);
        proc(b.z, b.w, c.x, c.y, c.z, ss.y);
        pp = nx; a = na; b = nb; c = nc2; ss = nss;
    }
    if ((npix & 1) && tid == 0) {
        long long i = npix - 1;
        proc(logits[i * 6 + 0], logits[i * 6 + 1], logits[i * 6 + 2],
             logits[i * 6 + 3], logits[i * 6 + 4], sp[i]);
    }
    __syncthreads();

    if (!direct) {
        unsigned long long* myc = copies + (long long)blockIdx.x * COPYU;
        for (int i = threadIdx.x; i < NSEG / 2; i += BLK_B) {
            ((ulonglong2*)myc)[i]          = ((ulonglong2*)hist)[i];
            ((ulonglong2*)(myc + NSEG))[i] = ((ulonglong2*)(hist + PADU))[i];
        }
    } else {
        for (int i = threadIdx.x; i < NSEG; i += BLK_B) {
            unsigned long long v = hist[i];
            atomicAdd(&Rs1[i],            (unsigned)(v & 0xFFFFu));
            atomicAdd(&Rs1[NSEG + i],     (unsigned)((v >> 16) & 0xFFFFu));
            atomicAdd(&Rs1[2 * NSEG + i], (unsigned)((v >> 32) & 0xFFFFu));
            atomicAdd(&Rs1[3 * NSEG + i], (unsigned)(v >> 48));
            atomicAdd(&Rc[i], hist[PADU + i]);
        }
    }

    for (int off = 32; off; off >>= 1) ent += __shfl_down(ent, off);
    int wid = threadIdx.x >> 6, lid = threadIdx.x & 63;
    if (lid == 0) wred[wid] = ent;
    __syncthreads();
    if (threadIdx.x == 0) {
        float s = 0.f;
        for (int i = 0; i < BLK_B / 64; ++i) s += wred[i];
        Epart[blockIdx.x] = s;
    }
}

// ===== ABLATION PROBE (output discarded): identical loop, atomics removed =====
// asm keep-alives hold the packed values live (prevents DCE of softmax/packing,
// rule: ablation-via-skip DCEs upstream ops). Flush of (zero) hist preserved so
// store traffic matches. dur_us delta vs r10 isolates the atomic cost.
__launch_bounds__(BLK_B, 1)
__global__ void mrf_main_nA(const float* __restrict__ logits,
                            const int* __restrict__ sp,
                            long long npix,
                            unsigned long long* __restrict__ copies2,
                            float* __restrict__ Eg)
{
    __shared__ alignas(16) unsigned long long hist[2 * PADU];
    __shared__ float wred[BLK_B / 64];

    for (int i = threadIdx.x; i < 2 * PADU; i += BLK_B) hist[i] = 0ull;
    __syncthreads();

    float ent = 0.f;

    auto proc = [&](float x0, float x1, float x2, float x3, float x4, int seg) {
        float m  = fmaxf(fmaxf(x0, x1), fmaxf(fmaxf(x2, x3), x4));
        float d0 = x0 - m, d1 = x1 - m, d2 = x2 - m, d3 = x3 - m, d4 = x4 - m;
        float t0 = __expf(d0), t1 = __expf(d1), t2 = __expf(d2),
              t3 = __expf(d3), t4 = __expf(d4);
        float S = ((t0 + t1) + (t2 + t3)) + t4;
        float r = __builtin_amdgcn_rcpf(S);
        float p0 = t0 * r, p1 = t1 * r, p2 = t2 * r, p3 = t3 * r, p4 = t4 * r;
        ent += __logf(S) - r * (t0 * d0 + t1 * d1 + t2 * d2 + t3 * d3 + t4 * d4);
        float s2 = ((p0 * p0 + p1 * p1) + (p2 * p2 + p3 * p3)) + p4 * p4;
        unsigned long long q0 = (unsigned)(p0 * FIXA + 0.5f);
        unsigned long long q1 = (unsigned)(p1 * FIXA + 0.5f);
        unsigned long long q2 = (unsigned)(p2 * FIXA + 0.5f);
        unsigned long long q3 = (unsigned)(p3 * FIXA + 0.5f);
        unsigned long long qs = (unsigned)(s2 * FIXC + 0.5f);
        unsigned long long pa = q0 | (q1 << 16) | (q2 << 32) | (q3 << 48);
        unsigned long long pc = 0x100000000ull | qs;
        asm volatile("" :: "v"((unsigned)pa), "v"((unsigned)(pa >> 32)),
                           "v"((unsigned)pc), "v"((unsigned)(pc >> 32)),
                           "v"(seg));
    };

    long long tid    = (long long)blockIdx.x * BLK_B + threadIdx.x;
    long long stride = (long long)gridDim.x * BLK_B;
    long long npair  = npix >> 1;

    float4 a, b, c; int2 ss;
    long long pp = tid;
    if (pp < npair) {
        const float4* base = (const float4*)(logits + pp * 12);
        a = base[0]; b = base[1]; c = base[2];
        ss = *(const int2*)(sp + pp * 2);
    }
    while (pp < npair) {
        long long nx = pp + stride;
        float4 na, nb, nc2; int2 nss;
        if (nx < npair) {
            const float4* base = (const float4*)(logits + nx * 12);
            na = base[0]; nb = base[1]; nc2 = base[2];
            nss = *(const int2*)(sp + nx * 2);
        }
        proc(a.x, a.y, a.z, a.w, b.x, ss.x);
        proc(b.z, b.w, c.x, c.y, c.z, ss.y);
        pp = nx; a = na; b = nb; c = nc2; ss = nss;
    }
    if ((npix & 1) && tid == 0) {
        long long i = npix - 1;
        proc(logits[i * 6 + 0], logits[i * 6 + 1], logits[i * 6 + 2],
             logits[i * 6 + 3], logits[i * 6 + 4], sp[i]);
    }
    __syncthreads();

    unsigned long long* myc = copies2 + (long long)blockIdx.x * COPYU;
    for (int i = threadIdx.x; i < NSEG / 2; i += BLK_B) {
        ((ulonglong2*)myc)[i]          = ((ulonglong2*)hist)[i];
        ((ulonglong2*)(myc + NSEG))[i] = ((ulonglong2*)(hist + PADU))[i];
    }

    for (int off = 32; off; off >>= 1) ent += __shfl_down(ent, off);
    int wid = threadIdx.x >> 6, lid = threadIdx.x & 63;
    if (lid == 0) wred[wid] = ent;
    __syncthreads();
    if (threadIdx.x == 0) {
        float s = 0.f;
        for (int i = 0; i < BLK_B / 64; ++i) s += wred[i];
        Eg[blockIdx.x] = s;
    }
}

__global__ void mrf_reduce(const unsigned long long* __restrict__ copies,
                           unsigned long long* __restrict__ Rc,
                           unsigned* __restrict__ Rs1, int ncopies)
{
    __shared__ unsigned           red[4][256];
    __shared__ unsigned long long redc[256];
    int lane = threadIdx.x & 31, chunk = threadIdx.x >> 5;
    int half = gridDim.x >> 1;
    if ((int)blockIdx.x < half) {
        int col = blockIdx.x * 32 + lane;
        unsigned a0 = 0, a1 = 0, a2 = 0, a3 = 0;
        #pragma unroll 4
        for (int c = chunk; c < ncopies; c += 8) {
            unsigned long long v = copies[(long long)c * COPYU + col];
            a0 += (unsigned)(v & 0xFFFFu);
            a1 += (unsigned)((v >> 16) & 0xFFFFu);
            a2 += (unsigned)((v >> 32) & 0xFFFFu);
            a3 += (unsigned)(v >> 48);
        }
        red[0][threadIdx.x] = a0; red[1][threadIdx.x] = a1;
        red[2][threadIdx.x] = a2; red[3][threadIdx.x] = a3;
        __syncthreads();
        if (chunk < 4) {
            red[0][threadIdx.x] += red[0][threadIdx.x + 128];
            red[1][threadIdx.x] += red[1][threadIdx.x + 128];
            red[2][threadIdx.x] += red[2][threadIdx.x + 128];
            red[3][threadIdx.x] += red[3][threadIdx.x + 128];
        }
        __syncthreads();
        if (chunk < 2) {
            red[0][threadIdx.x] += red[0][threadIdx.x + 64];
            red[1][threadIdx.x] += red[1][threadIdx.x + 64];
            red[2][threadIdx.x] += red[2][threadIdx.x + 64];
            red[3][threadIdx.x] += red[3][threadIdx.x + 64];
        }
        __syncthreads();
        if (chunk == 0) {
            Rs1[col]            = red[0][threadIdx.x] + red[0][threadIdx.x + 32];
            Rs1[NSEG + col]     = red[1][threadIdx.x] + red[1][threadIdx.x + 32];
            Rs1[2 * NSEG + col] = red[2][threadIdx.x] + red[2][threadIdx.x + 32];
            Rs1[3 * NSEG + col] = red[3][threadIdx.x] + red[3][threadIdx.x + 32];
        }
    } else {
        int col = (blockIdx.x - half) * 32 + lane;
        unsigned long long s = 0ull;
        #pragma unroll 4
        for (int c = chunk; c < ncopies; c += 8)
            s += copies[(long long)c * COPYU + NSEG + col];
        redc[threadIdx.x] = s;
        __syncthreads();
        if (chunk < 4) redc[threadIdx.x] += redc[threadIdx.x + 128];
        __syncthreads();
        if (chunk < 2) redc[threadIdx.x] += redc[threadIdx.x + 64];
        __syncthreads();
        if (chunk == 0) Rc[col] = redc[threadIdx.x] + redc[threadIdx.x + 32];
    }
}

__launch_bounds__(1024)
__global__ void mrf_final(const unsigned long long* __restrict__ Rc,
                          const unsigned* __restrict__ Rs1,
                          const float* __restrict__ E,
                          float* __restrict__ out, float invN, int nE)
{
    float smooth = 0.f, nsp = 0.f, entl = 0.f;
    for (int seg = threadIdx.x; seg < NSEG; seg += 1024) {
        unsigned long long C = Rc[seg];
        double cnt = (double)(unsigned)(C >> 32);
        double S2  = (double)(unsigned)(C) * INVC;
        double s10 = (double)Rs1[seg]            * INVA;
        double s11 = (double)Rs1[NSEG + seg]     * INVA;
        double s12 = (double)Rs1[2 * NSEG + seg] * INVA;
        double s13 = (double)Rs1[3 * NSEG + seg] * INVA;
        double s14 = cnt - ((s10 + s11) + (s12 + s13));
        if (cnt >= 2.0) {
            double sq  = ((s10 * s10 + s11 * s11) + (s12 * s12 + s13 * s13))
                         + s14 * s14;
            double var = (S2 - sq / cnt) / (cnt - 1.0);
            smooth += (float)(var * 0.2);
        }
        if (cnt > 0.0) nsp += 1.f;
    }
    for (int j = threadIdx.x; j < nE; j += 1024) entl += E[j];

    for (int off = 32; off; off >>= 1) {
        smooth += __shfl_down(smooth, off);
        nsp    += __shfl_down(nsp, off);
        entl   += __shfl_down(entl, off);
    }
    __shared__ float r1[16], r2[16], r3[16];
    int wid = threadIdx.x >> 6, lid = threadIdx.x & 63;
    if (lid == 0) { r1[wid] = smooth; r2[wid] = nsp; r3[wid] = entl; }
    __syncthreads();
    if (threadIdx.x == 0) {
        float S = 0.f, Np = 0.f, Et = 0.f;
        for (int i = 0; i < 16; ++i) { S += r1[i]; Np += r2[i]; Et += r3[i]; }
        out[0] = LAMBDA1 * (S / fmaxf(Np, 1.f)) + LAMBDA2 * (Et * invN);
    }
}

extern "C" void kernel_launch(void* const* d_in, const int* in_sizes, int n_in,
                              void* d_out, int out_size, void* d_ws, size_t ws_size,
                              hipStream_t stream)
{
    const float* logits = (const float*)d_in[0];
    const int*   sp     = (const int*)d_in[1];
    long long npix = (long long)in_sizes[1];

    // ws layout (u64): Rc[NSEG] | Rs1 4*NSEG u32 | E 128 | copies | copies2 | Eg
    unsigned long long* ws  = (unsigned long long*)d_ws;
    unsigned long long* Rc  = ws;
    unsigned*           Rs1 = (unsigned*)(ws + NSEG);
    float*              E   = (float*)(ws + 3 * NSEG);
    unsigned long long* copies  = ws + 3 * NSEG + 128;
    unsigned long long* copies2 = copies + (long long)GRID_B * COPYU;
    float*              Eg  = (float*)(copies2 + (long long)GRID_B * COPYU);

    long long availU = (long long)(ws_size / 8);
    bool haveCopies = availU >= 3 * NSEG + 128 + (long long)GRID_B * COPYU;
    bool haveProbe  = availU >= 3 * NSEG + 256 + 2 * (long long)GRID_B * COPYU;

    if (haveCopies) {
        mrf_main<<<GRID_B, BLK_B, 0, stream>>>(logits, sp, npix, copies,
                                               Rc, Rs1, E, 0);
        mrf_reduce<<<2 * (NSEG / 32), 256, 0, stream>>>(copies, Rc, Rs1, GRID_B);
    } else {
        hipMemsetAsync(ws, 0, (size_t)(3 * NSEG) * 8, stream);
        mrf_main<<<GRID_B, BLK_B, 0, stream>>>(logits, sp, npix, nullptr,
                                               Rc, Rs1, E, 1);
    }
    mrf_final<<<1, 1024, 0, stream>>>(Rc, Rs1, E, (float*)d_out,
                                      1.f / (float)npix, GRID_B);
    if (haveProbe) {
        // ablation probe, output discarded; placed last so it can't perturb
        // the real pipeline's cache state
        mrf_main_nA<<<GRID_B, BLK_B, 0, stream>>>(logits, sp, npix, copies2, Eg);
    }
}

// Round 14
// 165.813 us; speedup vs baseline: 1.1242x; 1.1242x over previous
//
#include <hip/hip_runtime.h>

#define NSEG   4096
#define GRID_B 256
#define BLK_B  1024
#define COPYU  (2 * NSEG)           // u64 per copy: A (4x16b Q10) | C (Q20|cnt)
#define PADU   (NSEG + 2)
#define LAMBDA1 0.8f
#define LAMBDA2 0.2f
#define FIXA   1024.0f              // Q10 for s1 fields
#define INVA   (1.0 / 1024.0)
#define FIXC   1048576.0f           // Q20 for S2
#define INVC   (1.0 / 1048576.0)

// Ledger: r6 10 f32 atomics/px: main=202us. r9 3 u64/px: main<56. r10 2/px:
// main~50 (no change vs r9 -> per-op model dead). r11 ablation: atomic-free
// floor F=20us (L3-BW-bound: 112MB/5.6TB/s); atomic increment ~30us
// (~2.4 cyc/lane = DS pipe throughput floor; 2/px is provably minimal).
// 50 = 20+30 serial => no overlap. Theory: per-wave IN-ORDER ISSUE -- r10's
// proc(px0) issues atomics before px1's softmax; DS-issue stall blocks the
// wave's subsequent VALU. Fix: compute BOTH softmaxes -> burst 4 atomics.
// Predict main 50 -> 35-40; null result => structural floor, ROOFLINE.

__launch_bounds__(BLK_B, 1)
__global__ void mrf_main(const float* __restrict__ logits,
                         const int* __restrict__ sp,
                         long long npix,
                         unsigned long long* __restrict__ copies,
                         unsigned long long* __restrict__ Rc,
                         unsigned* __restrict__ Rs1,
                         float* __restrict__ Epart,
                         int direct)
{
    __shared__ alignas(16) unsigned long long hist[2 * PADU];
    __shared__ float wred[BLK_B / 64];

    for (int i = threadIdx.x; i < 2 * PADU; i += BLK_B) hist[i] = 0ull;
    __syncthreads();

    float ent = 0.f;

    // compute-only: softmax + pack; NO ds ops (keeps VALU ahead of the burst)
    auto compute = [&](float x0, float x1, float x2, float x3, float x4,
                       unsigned long long& pa, unsigned long long& pc) {
        float m  = fmaxf(fmaxf(x0, x1), fmaxf(fmaxf(x2, x3), x4));
        float d0 = x0 - m, d1 = x1 - m, d2 = x2 - m, d3 = x3 - m, d4 = x4 - m;
        float t0 = __expf(d0), t1 = __expf(d1), t2 = __expf(d2),
              t3 = __expf(d3), t4 = __expf(d4);
        float S = ((t0 + t1) + (t2 + t3)) + t4;
        float r = __builtin_amdgcn_rcpf(S);
        float p0 = t0 * r, p1 = t1 * r, p2 = t2 * r, p3 = t3 * r, p4 = t4 * r;
        ent += __logf(S) - r * (t0 * d0 + t1 * d1 + t2 * d2 + t3 * d3 + t4 * d4);
        float s2 = ((p0 * p0 + p1 * p1) + (p2 * p2 + p3 * p3)) + p4 * p4;
        unsigned long long q0 = (unsigned)(p0 * FIXA + 0.5f);
        unsigned long long q1 = (unsigned)(p1 * FIXA + 0.5f);
        unsigned long long q2 = (unsigned)(p2 * FIXA + 0.5f);
        unsigned long long q3 = (unsigned)(p3 * FIXA + 0.5f);
        unsigned long long qs = (unsigned)(s2 * FIXC + 0.5f);
        pa = q0 | (q1 << 16) | (q2 << 32) | (q3 << 48);
        pc = 0x100000000ull | qs;                    // cnt in hi word
    };

    long long tid    = (long long)blockIdx.x * BLK_B + threadIdx.x;
    long long stride = (long long)gridDim.x * BLK_B;
    long long npair  = npix >> 1;

    float4 a, b, c; int2 ss;
    long long pp = tid;
    if (pp < npair) {
        const float4* base = (const float4*)(logits + pp * 12);
        a = base[0]; b = base[1]; c = base[2];
        ss = *(const int2*)(sp + pp * 2);
    }
    while (pp < npair) {
        long long nx = pp + stride;
        float4 na, nb, nc2; int2 nss;
        if (nx < npair) {                 // loads for i+1 fly over i's burst
            const float4* base = (const float4*)(logits + nx * 12);
            na = base[0]; nb = base[1]; nc2 = base[2];
            nss = *(const int2*)(sp + nx * 2);
        }
        // ---- compute phase: both pixels, zero DS ops ----
        unsigned long long pa0, pc0, pa1, pc1;
        int g0 = ss.x, g1 = ss.y;
        compute(a.x, a.y, a.z, a.w, b.x, pa0, pc0);
        compute(b.z, b.w, c.x, c.y, c.z, pa1, pc1);
        // ---- commit phase: burst all 4 atomics ----
        atomicAdd(&hist[g0], pa0);
        atomicAdd(&hist[PADU + g0], pc0);
        atomicAdd(&hist[g1], pa1);
        atomicAdd(&hist[PADU + g1], pc1);
        pp = nx; a = na; b = nb; c = nc2; ss = nss;
    }
    if ((npix & 1) && tid == 0) {
        long long i = npix - 1;
        unsigned long long pa, pc;
        compute(logits[i * 6 + 0], logits[i * 6 + 1], logits[i * 6 + 2],
                logits[i * 6 + 3], logits[i * 6 + 4], pa, pc);
        int g = sp[i];
        atomicAdd(&hist[g], pa);
        atomicAdd(&hist[PADU + g], pc);
    }
    __syncthreads();

    if (!direct) {
        unsigned long long* myc = copies + (long long)blockIdx.x * COPYU;
        for (int i = threadIdx.x; i < NSEG / 2; i += BLK_B) {
            ((ulonglong2*)myc)[i]          = ((ulonglong2*)hist)[i];
            ((ulonglong2*)(myc + NSEG))[i] = ((ulonglong2*)(hist + PADU))[i];
        }
    } else {
        for (int i = threadIdx.x; i < NSEG; i += BLK_B) {
            unsigned long long v = hist[i];
            atomicAdd(&Rs1[i],            (unsigned)(v & 0xFFFFu));
            atomicAdd(&Rs1[NSEG + i],     (unsigned)((v >> 16) & 0xFFFFu));
            atomicAdd(&Rs1[2 * NSEG + i], (unsigned)((v >> 32) & 0xFFFFu));
            atomicAdd(&Rs1[3 * NSEG + i], (unsigned)(v >> 48));
            atomicAdd(&Rc[i], hist[PADU + i]);
        }
    }

    for (int off = 32; off; off >>= 1) ent += __shfl_down(ent, off);
    int wid = threadIdx.x >> 6, lid = threadIdx.x & 63;
    if (lid == 0) wred[wid] = ent;
    __syncthreads();
    if (threadIdx.x == 0) {
        float s = 0.f;
        for (int i = 0; i < BLK_B / 64; ++i) s += wred[i];
        Epart[blockIdx.x] = s;
    }
}

__global__ void mrf_reduce(const unsigned long long* __restrict__ copies,
                           unsigned long long* __restrict__ Rc,
                           unsigned* __restrict__ Rs1, int ncopies)
{
    __shared__ unsigned           red[4][256];
    __shared__ unsigned long long redc[256];
    int lane = threadIdx.x & 31, chunk = threadIdx.x >> 5;
    int half = gridDim.x >> 1;
    if ((int)blockIdx.x < half) {
        int col = blockIdx.x * 32 + lane;
        unsigned a0 = 0, a1 = 0, a2 = 0, a3 = 0;
        #pragma unroll 4
        for (int c = chunk; c < ncopies; c += 8) {
            unsigned long long v = copies[(long long)c * COPYU + col];
            a0 += (unsigned)(v & 0xFFFFu);
            a1 += (unsigned)((v >> 16) & 0xFFFFu);
            a2 += (unsigned)((v >> 32) & 0xFFFFu);
            a3 += (unsigned)(v >> 48);
        }
        red[0][threadIdx.x] = a0; red[1][threadIdx.x] = a1;
        red[2][threadIdx.x] = a2; red[3][threadIdx.x] = a3;
        __syncthreads();
        if (chunk < 4) {
            red[0][threadIdx.x] += red[0][threadIdx.x + 128];
            red[1][threadIdx.x] += red[1][threadIdx.x + 128];
            red[2][threadIdx.x] += red[2][threadIdx.x + 128];
            red[3][threadIdx.x] += red[3][threadIdx.x + 128];
        }
        __syncthreads();
        if (chunk < 2) {
            red[0][threadIdx.x] += red[0][threadIdx.x + 64];
            red[1][threadIdx.x] += red[1][threadIdx.x + 64];
            red[2][threadIdx.x] += red[2][threadIdx.x + 64];
            red[3][threadIdx.x] += red[3][threadIdx.x + 64];
        }
        __syncthreads();
        if (chunk == 0) {
            Rs1[col]            = red[0][threadIdx.x] + red[0][threadIdx.x + 32];
            Rs1[NSEG + col]     = red[1][threadIdx.x] + red[1][threadIdx.x + 32];
            Rs1[2 * NSEG + col] = red[2][threadIdx.x] + red[2][threadIdx.x + 32];
            Rs1[3 * NSEG + col] = red[3][threadIdx.x] + red[3][threadIdx.x + 32];
        }
    } else {
        int col = (blockIdx.x - half) * 32 + lane;
        unsigned long long s = 0ull;
        #pragma unroll 4
        for (int c = chunk; c < ncopies; c += 8)
            s += copies[(long long)c * COPYU + NSEG + col];
        redc[threadIdx.x] = s;
        __syncthreads();
        if (chunk < 4) redc[threadIdx.x] += redc[threadIdx.x + 128];
        __syncthreads();
        if (chunk < 2) redc[threadIdx.x] += redc[threadIdx.x + 64];
        __syncthreads();
        if (chunk == 0) Rc[col] = redc[threadIdx.x] + redc[threadIdx.x + 32];
    }
}

__launch_bounds__(1024)
__global__ void mrf_final(const unsigned long long* __restrict__ Rc,
                          const unsigned* __restrict__ Rs1,
                          const float* __restrict__ E,
                          float* __restrict__ out, float invN, int nE)
{
    float smooth = 0.f, nsp = 0.f, entl = 0.f;
    for (int seg = threadIdx.x; seg < NSEG; seg += 1024) {
        unsigned long long C = Rc[seg];
        double cnt = (double)(unsigned)(C >> 32);
        double S2  = (double)(unsigned)(C) * INVC;
        double s10 = (double)Rs1[seg]            * INVA;
        double s11 = (double)Rs1[NSEG + seg]     * INVA;
        double s12 = (double)Rs1[2 * NSEG + seg] * INVA;
        double s13 = (double)Rs1[3 * NSEG + seg] * INVA;
        double s14 = cnt - ((s10 + s11) + (s12 + s13));
        if (cnt >= 2.0) {
            double sq  = ((s10 * s10 + s11 * s11) + (s12 * s12 + s13 * s13))
                         + s14 * s14;
            double var = (S2 - sq / cnt) / (cnt - 1.0);
            smooth += (float)(var * 0.2);
        }
        if (cnt > 0.0) nsp += 1.f;
    }
    for (int j = threadIdx.x; j < nE; j += 1024) entl += E[j];

    for (int off = 32; off; off >>= 1) {
        smooth += __shfl_down(smooth, off);
        nsp    += __shfl_down(nsp, off);
        entl   += __shfl_down(entl, off);
    }
    __shared__ float r1[16], r2[16], r3[16];
    int wid = threadIdx.x >> 6, lid = threadIdx.x & 63;
    if (lid == 0) { r1[wid] = smooth; r2[wid] = nsp; r3[wid] = entl; }
    __syncthreads();
    if (threadIdx.x == 0) {
        float S = 0.f, Np = 0.f, Et = 0.f;
        for (int i = 0; i < 16; ++i) { S += r1[i]; Np += r2[i]; Et += r3[i]; }
        out[0] = LAMBDA1 * (S / fmaxf(Np, 1.f)) + LAMBDA2 * (Et * invN);
    }
}

extern "C" void kernel_launch(void* const* d_in, const int* in_sizes, int n_in,
                              void* d_out, int out_size, void* d_ws, size_t ws_size,
                              hipStream_t stream)
{
    const float* logits = (const float*)d_in[0];
    const int*   sp     = (const int*)d_in[1];
    long long npix = (long long)in_sizes[1];

    // ws layout (u64): Rc[NSEG] | Rs1 4*NSEG u32 | E 128 | copies
    unsigned long long* ws  = (unsigned long long*)d_ws;
    unsigned long long* Rc  = ws;
    unsigned*           Rs1 = (unsigned*)(ws + NSEG);
    float*              E   = (float*)(ws + 3 * NSEG);
    unsigned long long* copies = ws + 3 * NSEG + 128;

    long long availU = (long long)(ws_size / 8);
    bool haveCopies = availU >= 3 * NSEG + 128 + (long long)GRID_B * COPYU;

    if (haveCopies) {
        mrf_main<<<GRID_B, BLK_B, 0, stream>>>(logits, sp, npix, copies,
                                               Rc, Rs1, E, 0);
        mrf_reduce<<<2 * (NSEG / 32), 256, 0, stream>>>(copies, Rc, Rs1, GRID_B);
    } else {
        hipMemsetAsync(ws, 0, (size_t)(3 * NSEG) * 8, stream);
        mrf_main<<<GRID_B, BLK_B, 0, stream>>>(logits, sp, npix, nullptr,
                                               Rc, Rs1, E, 1);
    }
    mrf_final<<<1, 1024, 0, stream>>>(Rc, Rs1, E, (float*)d_out,
                                      1.f / (float)npix, GRID_B);
}